// Round 6
// baseline (649.153 us; speedup 1.0000x reference)
//
#include <hip/hip_runtime.h>
#include <hip/hip_bf16.h>
#include <stdint.h>

// ---------- bf16 helpers (raw ushort representation) ----------
__device__ inline float bf2f(ushort u) {
    union { uint32_t u; float f; } v; v.u = ((uint32_t)u) << 16; return v.f;
}
__device__ inline ushort f2bf(float f) {
    union { float f; uint32_t u; } v; v.f = f;
    uint32_t u = v.u;
    uint32_t r = (u + 0x7fffu + ((u >> 16) & 1u)) >> 16;  // RNE
    return (ushort)r;
}
__device__ inline uint32_t pk2bf(uint32_t flo, uint32_t fhi) {  // two f32 bit-patterns -> packed bf16x2
    uint32_t lo = (flo + 0x7fffu + ((flo >> 16) & 1u)) >> 16;
    uint32_t hi = (fhi + 0x7fffu + ((fhi >> 16) & 1u)) >> 16;
    return lo | (hi << 16);
}

typedef __attribute__((ext_vector_type(8))) short bf16x8;
typedef __attribute__((ext_vector_type(4))) float f32x4;

// async global->LDS, 16B per lane; LDS dest must be wave-uniform base (HW adds lane*16)
__device__ inline void gload_lds16(const ushort* g, ushort* l) {
    __builtin_amdgcn_global_load_lds(
        (const __attribute__((address_space(1))) void*)g,
        (__attribute__((address_space(3))) void*)l, 16, 0, 0);
}

// ---------- weight transpose+cast: W[1024,1024] f32 -> Wt[1024,1024] bf16 ----------
__global__ void transpose1024(const float* __restrict__ Wq, const float* __restrict__ Wk,
                              const float* __restrict__ Wv, const float* __restrict__ Wo,
                              ushort* __restrict__ WqT, ushort* __restrict__ WkT,
                              ushort* __restrict__ WvT, ushort* __restrict__ WoT) {
    const float* in; ushort* out;
    switch (blockIdx.z) {
        case 0: in = Wq; out = WqT; break;
        case 1: in = Wk; out = WkT; break;
        case 2: in = Wv; out = WvT; break;
        default: in = Wo; out = WoT; break;
    }
    __shared__ ushort tile[64][65];
    const int t = threadIdx.x;
    const int c = t & 63, rq = t >> 6;
    const int bx = blockIdx.x * 64, by = blockIdx.y * 64;
#pragma unroll
    for (int i = 0; i < 16; ++i) {
        int r = i * 4 + rq;
        tile[r][c] = f2bf(in[(size_t)(by + r) * 1024 + bx + c]);
    }
    __syncthreads();
#pragma unroll
    for (int i = 0; i < 16; ++i) {
        int r = i * 4 + rq;
        out[(size_t)(bx + r) * 1024 + by + c] = tile[c][r];
    }
}

// ---------- x chunk cast: f32 -> bf16, 8 elems/thread, grid-stride ----------
__global__ __launch_bounds__(256)
void cast_bf16(const float* __restrict__ in, ushort* __restrict__ out, size_t n8) {
    size_t i = (size_t)blockIdx.x * blockDim.x + threadIdx.x;
    const size_t stride = (size_t)gridDim.x * blockDim.x;
    for (; i < n8; i += stride) {
        const uint4 lo = *(const uint4*)&in[i * 8];
        const uint4 hi = *(const uint4*)&in[i * 8 + 4];
        uint4 o;
        o.x = pk2bf(lo.x, lo.y); o.y = pk2bf(lo.z, lo.w);
        o.z = pk2bf(hi.x, hi.y); o.w = pk2bf(hi.z, hi.w);
        *(uint4*)&out[i * 8] = o;
    }
}

// ---------- persistent 256x256 8-phase bf16 GEMM: C[M,N] = A[M,K] @ Bt[N,K]^T ----------
// T2 (granule XOR swizzle, 0 conflicts measured) + T3+T4 (counted vmcnt) + T5 (setprio)
// + PERSISTENT MULTI-TILE (this round): each block owns T consecutive output tiles
// (tid = wg*T + i, same m-row -> A panel L1/L2-resident on re-stage). The staging
// pipeline runs over global iteration g = tile*NT + kt WITHOUT a drain at tile
// boundaries: at a tile's last K-step the next tile's first half-tiles are already
// in flight. vmcnt ledger identical to the single-tile version (2 half-tiles ahead,
// vmcnt(4) at P1/P3; vmcnt(0) only at the final iteration). Per-tile epilogue
// (C-write + acc reset) slots after P3's barrier; its stores make the following
// vmcnt(4) conservatively drain them (in-order retirement) - correct, ~700cy.
template <bool C_F32>
__global__ __launch_bounds__(512, 2)
void gemm256(const ushort* __restrict__ A, int lda, const ushort* __restrict__ Bt,
             void* __restrict__ C_, int M, int N, int K, int T) {
    __shared__ __attribute__((aligned(16))) ushort lds[65536];  // 128 KiB
    const int t = threadIdx.x;
    const int lane = t & 63, wave = t >> 6;
    const int wm = wave >> 2, wn = wave & 3;       // 2 x 4 wave grid
    const int quad = lane >> 4, l16 = lane & 15;
    const int gx = N >> 8;
    const int wg = blockIdx.x;

    const f32x4 zero = {0.f, 0.f, 0.f, 0.f};
    f32x4 acc[8][4];
#pragma unroll
    for (int i = 0; i < 8; ++i)
#pragma unroll
        for (int j = 0; j < 4; ++j) acc[i][j] = zero;

    // stage one 16 KB half-tile: 2 gload_lds per thread (1024 granules = 256 rows x 4)
    // T2: pre-swizzle the global source granule so linear LDS slot (row, gp)
    // holds logical granule gp ^ ((row>>1)&3).
    auto STAGE = [&](const ushort* __restrict__ src, int ldb, int rc0, int kcol,
                     int regio, int buf) {
        ushort* l = &lds[buf * 32768 + regio];
#pragma unroll
        for (int j = 0; j < 2; ++j) {
            const int g = j * 512 + t;
            const int r = g >> 2;
            const int cg = (((g & 3) ^ ((r >> 1) & 3)) * 8);
            gload_lds16(&src[(size_t)(rc0 + r) * ldb + kcol + cg],
                        &l[(j * 512 + wave * 64) * 8]);
        }
    };
    // swizzled ds_read offset for logical (row R, granule quad)
    auto LOFF = [&](int R) { return R * 32 + (quad ^ ((R >> 1) & 3)) * 8; };

    const int NT = K >> 6;
    const int GEND = T * NT;

    // current tile coords
    int tidc = wg * T;
    int mC = (tidc / gx) << 8, nC = (tidc % gx) << 8;

    // ---- prologue: stage iteration 0 (all 4 halves), retire A-k0/B-k0 ----
    STAGE(A, lda, mC, 0, 0, 0);
    STAGE(Bt, K, nC, 0, 16384, 0);
    STAGE(A, lda, mC, 32, 8192, 0);
    STAGE(Bt, K, nC, 32, 24576, 0);
    asm volatile("s_waitcnt vmcnt(4)" ::: "memory");
    __builtin_amdgcn_s_barrier();

    int cur = 0;
    for (int g = 0; g < GEND; ++g) {
        const bool nx = g + 1 < GEND;
        // staging target: iteration g+1 (possibly next tile, kt=0)
        const int i2 = (g + 1) / NT, kt2 = (g + 1) - i2 * NT;
        const int tidS = wg * T + i2;
        const int mS = ((tidS / gx) << 8), nS = ((tidS % gx) << 8);
        const int kS = kt2 << 6;
        const bool tb = (kt2 == 0);                 // g is a tile's last K-step

        const ushort* la0 = &lds[cur * 32768];
        const ushort* lb0 = &lds[cur * 32768 + 16384];
        const ushort* la1 = la0 + 8192;
        const ushort* lb1 = lb0 + 8192;
        bf16x8 af[4], bf[4];

        // ================= P0: ks0, mt 0-3 =================
#pragma unroll
        for (int i = 0; i < 4; ++i) {
            af[i] = *(const bf16x8*)&la0[LOFF(wm * 128 + i * 16 + l16)];
            bf[i] = *(const bf16x8*)&lb0[LOFF(wn * 64 + i * 16 + l16)];
        }
        if (nx) STAGE(A, lda, mS, kS, 0, cur ^ 1);
        __builtin_amdgcn_sched_barrier(0);
        __builtin_amdgcn_s_barrier();
        asm volatile("s_waitcnt lgkmcnt(0)" ::: "memory");
        __builtin_amdgcn_sched_barrier(0);
        __builtin_amdgcn_s_setprio(1);
#pragma unroll
        for (int i = 0; i < 4; ++i)
#pragma unroll
            for (int n = 0; n < 4; ++n)
                acc[i][n] = __builtin_amdgcn_mfma_f32_16x16x32_bf16(af[i], bf[n], acc[i][n], 0, 0, 0);
        __builtin_amdgcn_s_setprio(0);
        __builtin_amdgcn_sched_barrier(0);
        __builtin_amdgcn_s_barrier();

        // ================= P1: ks0, mt 4-7 =================
#pragma unroll
        for (int i = 0; i < 4; ++i)
            af[i] = *(const bf16x8*)&la0[LOFF(wm * 128 + (i + 4) * 16 + l16)];
        if (nx) STAGE(Bt, K, nS, kS, 16384, cur ^ 1);
        __builtin_amdgcn_sched_barrier(0);
        __builtin_amdgcn_s_barrier();
        asm volatile("s_waitcnt lgkmcnt(0)" ::: "memory");
        __builtin_amdgcn_sched_barrier(0);
        __builtin_amdgcn_s_setprio(1);
#pragma unroll
        for (int i = 0; i < 4; ++i)
#pragma unroll
            for (int n = 0; n < 4; ++n)
                acc[i + 4][n] = __builtin_amdgcn_mfma_f32_16x16x32_bf16(af[i], bf[n], acc[i + 4][n], 0, 0, 0);
        __builtin_amdgcn_s_setprio(0);
        if (nx) asm volatile("s_waitcnt vmcnt(4)" ::: "memory");
        else    asm volatile("s_waitcnt vmcnt(0)" ::: "memory");
        __builtin_amdgcn_sched_barrier(0);
        __builtin_amdgcn_s_barrier();

        // ================= P2: ks1, mt 0-3 =================
#pragma unroll
        for (int i = 0; i < 4; ++i) {
            af[i] = *(const bf16x8*)&la1[LOFF(wm * 128 + i * 16 + l16)];
            bf[i] = *(const bf16x8*)&lb1[LOFF(wn * 64 + i * 16 + l16)];
        }
        if (nx) STAGE(A, lda, mS, kS + 32, 8192, cur ^ 1);
        __builtin_amdgcn_sched_barrier(0);
        __builtin_amdgcn_s_barrier();
        asm volatile("s_waitcnt lgkmcnt(0)" ::: "memory");
        __builtin_amdgcn_sched_barrier(0);
        __builtin_amdgcn_s_setprio(1);
#pragma unroll
        for (int i = 0; i < 4; ++i)
#pragma unroll
            for (int n = 0; n < 4; ++n)
                acc[i][n] = __builtin_amdgcn_mfma_f32_16x16x32_bf16(af[i], bf[n], acc[i][n], 0, 0, 0);
        __builtin_amdgcn_s_setprio(0);
        __builtin_amdgcn_sched_barrier(0);
        __builtin_amdgcn_s_barrier();

        // ================= P3: ks1, mt 4-7 =================
#pragma unroll
        for (int i = 0; i < 4; ++i)
            af[i] = *(const bf16x8*)&la1[LOFF(wm * 128 + (i + 4) * 16 + l16)];
        if (nx) STAGE(Bt, K, nS, kS + 32, 24576, cur ^ 1);
        __builtin_amdgcn_sched_barrier(0);
        __builtin_amdgcn_s_barrier();
        asm volatile("s_waitcnt lgkmcnt(0)" ::: "memory");
        __builtin_amdgcn_sched_barrier(0);
        __builtin_amdgcn_s_setprio(1);
#pragma unroll
        for (int i = 0; i < 4; ++i)
#pragma unroll
            for (int n = 0; n < 4; ++n)
                acc[i + 4][n] = __builtin_amdgcn_mfma_f32_16x16x32_bf16(af[i], bf[n], acc[i + 4][n], 0, 0, 0);
        __builtin_amdgcn_s_setprio(0);
        if (nx) asm volatile("s_waitcnt vmcnt(4)" ::: "memory");
        __builtin_amdgcn_sched_barrier(0);
        __builtin_amdgcn_s_barrier();

        cur ^= 1;

        // ---- per-tile epilogue at tile boundary; pipeline for g+1 stays in flight ----
        if (tb) {
#pragma unroll
            for (int mt2 = 0; mt2 < 8; ++mt2)
#pragma unroll
                for (int nt2 = 0; nt2 < 4; ++nt2)
#pragma unroll
                    for (int r4 = 0; r4 < 4; ++r4) {
                        const int row = mC + wm * 128 + mt2 * 16 + quad * 4 + r4;
                        const int col = nC + wn * 64 + nt2 * 16 + l16;
                        if (C_F32) ((float*)C_)[(size_t)row * N + col] = acc[mt2][nt2][r4];
                        else       ((ushort*)C_)[(size_t)row * N + col] = f2bf(acc[mt2][nt2][r4]);
                    }
#pragma unroll
            for (int i = 0; i < 8; ++i)
#pragma unroll
                for (int j = 0; j < 4; ++j) acc[i][j] = zero;
            mC = mS; nC = nS;
        }
    }
}

// ---------- MFMA attention ----------
// Block = (b,h) 64x64 tile, 4 waves, wave w owns q rows [16w,16w+16).
// No Q/K/V LDS staging (each element read once; L2/L3-resident).
// QK: [tokens, 2048] bf16, Q at cols 0..1023 (h*64+d), K at cols 1024..2047.
// Vt: [1024, CROWS]  bf16, row f=h*64+d, col token.
// O overwrites the Q half in-place (safe: all Q/K reads complete before the
// P-repack __syncthreads; O region of block (b,h) read only by itself).
__global__ __launch_bounds__(256)
void attn_mfma(ushort* __restrict__ QK, const ushort* __restrict__ Vt,
               const float* __restrict__ bias, int CROWS) {
    const int t = threadIdx.x;
    const int lane = t & 63, wave = t >> 6;
    const int quad = lane >> 4, l16 = lane & 15;
    const int b = blockIdx.x >> 4, h = blockIdx.x & 15;
    const int SQK = 2048;
    const size_t qbase = (size_t)b * 64 * SQK + (size_t)h * 64;
    const size_t kbase = qbase + 1024;
    const size_t vbase = (size_t)(h * 64) * CROWS + (size_t)b * 64;

    __shared__ __attribute__((aligned(16))) ushort Pl[4 * 16 * 72];  // per-wave P[16][64], pad 72

    // ---- Q fragments: row=l16 (q within band), k(d)=ks*32+quad*8 ----
    bf16x8 qf[2];
#pragma unroll
    for (int ks = 0; ks < 2; ++ks)
        qf[ks] = *(const bf16x8*)&QK[qbase + (size_t)(wave * 16 + l16) * SQK + ks * 32 + quad * 8];

    // ---- S = Q K^T (contraction over d=64): M=16 q, N=64 kt ----
    const f32x4 zero = {0.f, 0.f, 0.f, 0.f};
    f32x4 s[4];
#pragma unroll
    for (int nt = 0; nt < 4; ++nt) s[nt] = zero;
#pragma unroll
    for (int nt = 0; nt < 4; ++nt)
#pragma unroll
        for (int ks = 0; ks < 2; ++ks) {
            bf16x8 kf = *(const bf16x8*)&QK[kbase + (size_t)(nt * 16 + l16) * SQK + ks * 32 + quad * 8];
            s[nt] = __builtin_amdgcn_mfma_f32_16x16x32_bf16(qf[ks], kf, s[nt], 0, 0, 0);
        }

    // ---- scale + bias; acc layout: row q = quad*4+r4 (+wave band), col kt = nt*16+l16 ----
    const int q0 = wave * 16 + quad * 4;
    float p[4][4];  // [nt][r4]
#pragma unroll
    for (int nt = 0; nt < 4; ++nt)
#pragma unroll
        for (int r4 = 0; r4 < 4; ++r4)
            p[nt][r4] = s[nt][r4] * 0.125f +
                        bias[(size_t)(h * 64 + q0 + r4) * 64 + nt * 16 + l16];

    // ---- row softmax: reduce over nt then across the 16 lanes of the quad ----
    float rinv[4];
#pragma unroll
    for (int r4 = 0; r4 < 4; ++r4) {
        float m = fmaxf(fmaxf(p[0][r4], p[1][r4]), fmaxf(p[2][r4], p[3][r4]));
        m = fmaxf(m, __shfl_xor(m, 1));
        m = fmaxf(m, __shfl_xor(m, 2));
        m = fmaxf(m, __shfl_xor(m, 4));
        m = fmaxf(m, __shfl_xor(m, 8));
#pragma unroll
        for (int nt = 0; nt < 4; ++nt) p[nt][r4] = __expf(p[nt][r4] - m);
        float sum = p[0][r4] + p[1][r4] + p[2][r4] + p[3][r4];
        sum += __shfl_xor(sum, 1);
        sum += __shfl_xor(sum, 2);
        sum += __shfl_xor(sum, 4);
        sum += __shfl_xor(sum, 8);
        rinv[r4] = 1.f / sum;
    }

    // ---- repack P to bf16 in LDS for the PV A-operand ----
#pragma unroll
    for (int nt = 0; nt < 4; ++nt)
#pragma unroll
        for (int r4 = 0; r4 < 4; ++r4)
            Pl[(wave * 16 + quad * 4 + r4) * 72 + nt * 16 + l16] = f2bf(p[nt][r4]);
    __syncthreads();

    // ---- O = P V (contraction over kt=64): M=16 q, N=64 d ----
    bf16x8 pa[2];
#pragma unroll
    for (int ks = 0; ks < 2; ++ks)
        pa[ks] = *(const bf16x8*)&Pl[(wave * 16 + l16) * 72 + ks * 32 + quad * 8];
    f32x4 o[4];
#pragma unroll
    for (int nt = 0; nt < 4; ++nt) o[nt] = zero;
#pragma unroll
    for (int nt = 0; nt < 4; ++nt)
#pragma unroll
        for (int ks = 0; ks < 2; ++ks) {
            bf16x8 vf = *(const bf16x8*)&Vt[vbase + (size_t)(nt * 16 + l16) * CROWS + ks * 32 + quad * 8];
            o[nt] = __builtin_amdgcn_mfma_f32_16x16x32_bf16(pa[ks], vf, o[nt], 0, 0, 0);
        }

    // ---- write O (deferred 1/l scaling) into Q half ----
#pragma unroll
    for (int nt = 0; nt < 4; ++nt)
#pragma unroll
        for (int r4 = 0; r4 < 4; ++r4)
            QK[qbase + (size_t)(q0 + r4) * SQK + nt * 16 + l16] = f2bf(o[nt][r4] * rinv[r4]);
}

extern "C" void kernel_launch(void* const* d_in, const int* in_sizes, int n_in,
                              void* d_out, int out_size, void* d_ws, size_t ws_size,
                              hipStream_t stream) {
    const float* x    = (const float*)d_in[0];   // [512,64,1024] f32
    const float* bias = (const float*)d_in[1];   // [1,16,64,64]  f32
    const float* Wq   = (const float*)d_in[2];
    const float* Wk   = (const float*)d_in[3];
    const float* Wv   = (const float*)d_in[4];
    const float* Wo   = (const float*)d_in[5];
    float* out = (float*)d_out;                  // [512,64,1024] f32

    const size_t D = 1024;
    const size_t WB = 4 * D * D * 2;             // 8.39 MB bf16 weights

    // ws-size-adaptive chunking: per chunk need CROWS*(2048+1024)*2 bytes after weights.
    int CHUNK_B = 128;                           // known-fit fallback (58.7 MB total)
    if (ws_size >= WB + (size_t)512 * 64 * 6144)      CHUNK_B = 512;
    else if (ws_size >= WB + (size_t)256 * 64 * 6144) CHUNK_B = 256;
    const int NCHUNK = 512 / CHUNK_B;
    const size_t CROWS = (size_t)CHUNK_B * 64;
    const size_t CELEM = CROWS * D;

    // ws layout: WqT|WkT (adjacent => fused [2048][1024]) | WvT | WoT | QKc | Vtc
    ushort* WqT = (ushort*)d_ws;
    ushort* WkT = WqT + D * D;
    ushort* WvT = WkT + D * D;
    ushort* WoT = WvT + D * D;
    ushort* QKc = WoT + D * D;                   // [CROWS][2048] bf16
    ushort* Vtc = QKc + CROWS * 2048;            // [1024][CROWS] bf16

    transpose1024<<<dim3(16, 16, 4), 256, 0, stream>>>(Wq, Wk, Wv, Wo, WqT, WkT, WvT, WoT);

    // persistent-tile helper: T tiles per block, grid = NTILE/T (target 256 blocks)
    auto tilesT = [](int ntile) { return ntile >= 256 ? ntile / 256 : 1; };

    for (int c = 0; c < NCHUNK; ++c) {
        const float* xc = x + (size_t)c * CELEM;
        float* outc = out + (size_t)c * CELEM;
        ushort* Xc = (ushort*)outc;              // scratch: consumed before final GEMM writes
        cast_bf16<<<2048, 256, 0, stream>>>(xc, Xc, CELEM / 8);

        // fused Q|K projection: NTILE = (CROWS/256) * 8
        {
            const int ntile = (int)(CROWS / 256) * 8, T = tilesT(ntile);
            gemm256<false><<<ntile / T, 512, 0, stream>>>(
                Xc, 1024, WqT, QKc, (int)CROWS, 2048, 1024, T);
        }
        // transposed V projection: Vt[f][t], NTILE = 4 * (CROWS/256)
        {
            const int ntile = 4 * (int)(CROWS / 256), T = tilesT(ntile);
            gemm256<false><<<ntile / T, 512, 0, stream>>>(
                WvT, 1024, Xc, Vtc, 1024, (int)CROWS, 1024, T);
        }
        // attention: O overwrites Q half of QKc
        attn_mfma<<<CHUNK_B * 16, 256, 0, stream>>>(QKc, Vtc, bias, (int)CROWS);
        // output projection: A = O (Q half, lda=2048), NTILE = (CROWS/256) * 4
        {
            const int ntile = (int)(CROWS / 256) * 4, T = tilesT(ntile);
            gemm256<true><<<ntile / T, 512, 0, stream>>>(
                QKc, 2048, WoT, outc, (int)CROWS, 1024, 1024, T);
        }
    }
}

// Round 7
// 610.468 us; speedup vs baseline: 1.0634x; 1.0634x over previous
//
#include <hip/hip_runtime.h>
#include <hip/hip_bf16.h>
#include <stdint.h>

// ---------- bf16 helpers (raw ushort representation) ----------
__device__ inline float bf2f(ushort u) {
    union { uint32_t u; float f; } v; v.u = ((uint32_t)u) << 16; return v.f;
}
__device__ inline ushort f2bf(float f) {
    union { float f; uint32_t u; } v; v.f = f;
    uint32_t u = v.u;
    uint32_t r = (u + 0x7fffu + ((u >> 16) & 1u)) >> 16;  // RNE
    return (ushort)r;
}
__device__ inline uint32_t pk2bf(uint32_t flo, uint32_t fhi) {  // two f32 bit-patterns -> packed bf16x2
    uint32_t lo = (flo + 0x7fffu + ((flo >> 16) & 1u)) >> 16;
    uint32_t hi = (fhi + 0x7fffu + ((fhi >> 16) & 1u)) >> 16;
    return lo | (hi << 16);
}

typedef __attribute__((ext_vector_type(8))) short bf16x8;
typedef __attribute__((ext_vector_type(4))) float f32x4;

// async global->LDS, 16B per lane; LDS dest must be wave-uniform base (HW adds lane*16)
__device__ inline void gload_lds16(const ushort* g, ushort* l) {
    __builtin_amdgcn_global_load_lds(
        (const __attribute__((address_space(1))) void*)g,
        (__attribute__((address_space(3))) void*)l, 16, 0, 0);
}

// ---------- weight transpose+cast: W[1024,1024] f32 -> Wt[1024,1024] bf16 ----------
__global__ void transpose1024(const float* __restrict__ Wq, const float* __restrict__ Wk,
                              const float* __restrict__ Wv, const float* __restrict__ Wo,
                              ushort* __restrict__ WqT, ushort* __restrict__ WkT,
                              ushort* __restrict__ WvT, ushort* __restrict__ WoT) {
    const float* in; ushort* out;
    switch (blockIdx.z) {
        case 0: in = Wq; out = WqT; break;
        case 1: in = Wk; out = WkT; break;
        case 2: in = Wv; out = WvT; break;
        default: in = Wo; out = WoT; break;
    }
    __shared__ ushort tile[64][65];
    const int t = threadIdx.x;
    const int c = t & 63, rq = t >> 6;
    const int bx = blockIdx.x * 64, by = blockIdx.y * 64;
#pragma unroll
    for (int i = 0; i < 16; ++i) {
        int r = i * 4 + rq;
        tile[r][c] = f2bf(in[(size_t)(by + r) * 1024 + bx + c]);
    }
    __syncthreads();
#pragma unroll
    for (int i = 0; i < 16; ++i) {
        int r = i * 4 + rq;
        out[(size_t)(bx + r) * 1024 + by + c] = tile[c][r];
    }
}

// ---------- x chunk cast: f32 -> bf16, 8 elems/thread, grid-stride ----------
__global__ __launch_bounds__(256)
void cast_bf16(const float* __restrict__ in, ushort* __restrict__ out, size_t n8) {
    size_t i = (size_t)blockIdx.x * blockDim.x + threadIdx.x;
    const size_t stride = (size_t)gridDim.x * blockDim.x;
    for (; i < n8; i += stride) {
        const uint4 lo = *(const uint4*)&in[i * 8];
        const uint4 hi = *(const uint4*)&in[i * 8 + 4];
        uint4 o;
        o.x = pk2bf(lo.x, lo.y); o.y = pk2bf(lo.z, lo.w);
        o.z = pk2bf(hi.x, hi.y); o.w = pk2bf(hi.z, hi.w);
        *(uint4*)&out[i * 8] = o;
    }
}

// ---------- 256x256 8-phase bf16 GEMM: C[M,N] = A[M,K] @ Bt[N,K]^T ----------
// T2 (granule XOR swizzle, 0 conflicts measured) + T3+T4 (counted vmcnt) + T5 (setprio)
// + T1 (bijective XCD swizzle). Round 7 change: REMOVED the explicit
// `s_waitcnt lgkmcnt(0)` + `sched_barrier(0)` fences around the MFMA clusters.
// The compiler now emits counted lgkmcnt(N) waits, so a wave's first MFMAs
// overlap its own remaining ds_read service (the fences forced LDS service
// [~2.3k cyc/K-tile/CU] and MFMA [~2.5k cyc] to fully serialize — the measured
// 38% MfmaUtil ceiling). dbuf correctness needs only the tile-boundary
// counted-vmcnt + s_barrier, both kept.
template <bool C_F32>
__global__ __launch_bounds__(512, 2)
void gemm256(const ushort* __restrict__ A, int lda, const ushort* __restrict__ Bt,
             void* __restrict__ C_, int M, int N, int K) {
    __shared__ __attribute__((aligned(16))) ushort lds[65536];  // 128 KiB
    const int t = threadIdx.x;
    const int lane = t & 63, wave = t >> 6;
    const int wm = wave >> 2, wn = wave & 3;       // 2 x 4 wave grid
    const int quad = lane >> 4, l16 = lane & 15;

    // bijective XCD swizzle (m204) on linear tile id
    const int gx = N >> 8;
    const int nwg = gridDim.x * gridDim.y;
    int wg = blockIdx.y * gridDim.x + blockIdx.x;
    {
        const int q = nwg >> 3, r = nwg & 7;
        const int xcd = wg & 7, loc = wg >> 3;
        wg = (xcd < r ? xcd * (q + 1) : r * (q + 1) + (xcd - r) * q) + loc;
    }
    const int m0 = (wg / gx) << 8, n0 = (wg % gx) << 8;

    const f32x4 zero = {0.f, 0.f, 0.f, 0.f};
    f32x4 acc[8][4];
#pragma unroll
    for (int i = 0; i < 8; ++i)
#pragma unroll
        for (int j = 0; j < 4; ++j) acc[i][j] = zero;

    // stage one 16 KB half-tile: 2 gload_lds per thread (1024 granules = 256 rows x 4)
    // T2: pre-swizzle the global source granule so linear LDS slot (row, gp)
    // holds logical granule gp ^ ((row>>1)&3).
    auto STAGE = [&](const ushort* __restrict__ src, int ldb, int rc0, int kcol,
                     int regio, int buf) {
        ushort* l = &lds[buf * 32768 + regio];
#pragma unroll
        for (int j = 0; j < 2; ++j) {
            const int g = j * 512 + t;
            const int r = g >> 2;
            const int cg = (((g & 3) ^ ((r >> 1) & 3)) * 8);
            gload_lds16(&src[(size_t)(rc0 + r) * ldb + kcol + cg],
                        &l[(j * 512 + wave * 64) * 8]);
        }
    };
    // swizzled ds_read offset for logical (row R, granule quad)
    auto LOFF = [&](int R) { return R * 32 + (quad ^ ((R >> 1) & 3)) * 8; };

    const int NT = K >> 6;
    // ---- prologue: stage tile 0 (all 4 halves), retire A-k0/B-k0 ----
    STAGE(A, lda, m0, 0, 0, 0);
    STAGE(Bt, K, n0, 0, 16384, 0);
    STAGE(A, lda, m0, 32, 8192, 0);
    STAGE(Bt, K, n0, 32, 24576, 0);
    asm volatile("s_waitcnt vmcnt(4)" ::: "memory");
    __builtin_amdgcn_s_barrier();

    int cur = 0;
    for (int kt = 0; kt < NT; ++kt) {
        const bool nx = kt + 1 < NT;
        const int kn = (kt + 1) << 6;
        const ushort* la0 = &lds[cur * 32768];
        const ushort* lb0 = &lds[cur * 32768 + 16384];
        const ushort* la1 = la0 + 8192;
        const ushort* lb1 = lb0 + 8192;
        bf16x8 af[4], bf[4];

        // ================= P0: ks0, mt 0-3 =================
#pragma unroll
        for (int i = 0; i < 4; ++i) {
            af[i] = *(const bf16x8*)&la0[LOFF(wm * 128 + i * 16 + l16)];
            bf[i] = *(const bf16x8*)&lb0[LOFF(wn * 64 + i * 16 + l16)];
        }
        if (nx) STAGE(A, lda, m0, kn, 0, cur ^ 1);
        __builtin_amdgcn_s_barrier();
        __builtin_amdgcn_s_setprio(1);
#pragma unroll
        for (int i = 0; i < 4; ++i)
#pragma unroll
            for (int n = 0; n < 4; ++n)
                acc[i][n] = __builtin_amdgcn_mfma_f32_16x16x32_bf16(af[i], bf[n], acc[i][n], 0, 0, 0);
        __builtin_amdgcn_s_setprio(0);
        __builtin_amdgcn_s_barrier();

        // ================= P1: ks0, mt 4-7 =================
#pragma unroll
        for (int i = 0; i < 4; ++i)
            af[i] = *(const bf16x8*)&la0[LOFF(wm * 128 + (i + 4) * 16 + l16)];
        if (nx) STAGE(Bt, K, n0, kn, 16384, cur ^ 1);
        __builtin_amdgcn_s_barrier();
        __builtin_amdgcn_s_setprio(1);
#pragma unroll
        for (int i = 0; i < 4; ++i)
#pragma unroll
            for (int n = 0; n < 4; ++n)
                acc[i + 4][n] = __builtin_amdgcn_mfma_f32_16x16x32_bf16(af[i], bf[n], acc[i + 4][n], 0, 0, 0);
        __builtin_amdgcn_s_setprio(0);
        if (nx) asm volatile("s_waitcnt vmcnt(4)" ::: "memory");
        else    asm volatile("s_waitcnt vmcnt(0)" ::: "memory");
        __builtin_amdgcn_s_barrier();

        // ================= P2: ks1, mt 0-3 =================
#pragma unroll
        for (int i = 0; i < 4; ++i) {
            af[i] = *(const bf16x8*)&la1[LOFF(wm * 128 + i * 16 + l16)];
            bf[i] = *(const bf16x8*)&lb1[LOFF(wn * 64 + i * 16 + l16)];
        }
        if (nx) STAGE(A, lda, m0, kn + 32, 8192, cur ^ 1);
        __builtin_amdgcn_s_barrier();
        __builtin_amdgcn_s_setprio(1);
#pragma unroll
        for (int i = 0; i < 4; ++i)
#pragma unroll
            for (int n = 0; n < 4; ++n)
                acc[i][n] = __builtin_amdgcn_mfma_f32_16x16x32_bf16(af[i], bf[n], acc[i][n], 0, 0, 0);
        __builtin_amdgcn_s_setprio(0);
        __builtin_amdgcn_s_barrier();

        // ================= P3: ks1, mt 4-7 =================
#pragma unroll
        for (int i = 0; i < 4; ++i)
            af[i] = *(const bf16x8*)&la1[LOFF(wm * 128 + (i + 4) * 16 + l16)];
        if (nx) STAGE(Bt, K, n0, kn + 32, 24576, cur ^ 1);
        __builtin_amdgcn_s_barrier();
        __builtin_amdgcn_s_setprio(1);
#pragma unroll
        for (int i = 0; i < 4; ++i)
#pragma unroll
            for (int n = 0; n < 4; ++n)
                acc[i + 4][n] = __builtin_amdgcn_mfma_f32_16x16x32_bf16(af[i], bf[n], acc[i + 4][n], 0, 0, 0);
        __builtin_amdgcn_s_setprio(0);
        if (nx) asm volatile("s_waitcnt vmcnt(4)" ::: "memory");
        __builtin_amdgcn_s_barrier();

        cur ^= 1;
    }

    // ---- epilogue: C/D layout col = lane&15, row = quad*4 + reg ----
#pragma unroll
    for (int mt = 0; mt < 8; ++mt)
#pragma unroll
        for (int nt = 0; nt < 4; ++nt)
#pragma unroll
            for (int r4 = 0; r4 < 4; ++r4) {
                const int row = m0 + wm * 128 + mt * 16 + quad * 4 + r4;
                const int col = n0 + wn * 64 + nt * 16 + l16;
                if (C_F32) ((float*)C_)[(size_t)row * N + col] = acc[mt][nt][r4];
                else       ((ushort*)C_)[(size_t)row * N + col] = f2bf(acc[mt][nt][r4]);
            }
}

// ---------- MFMA attention ----------
// Block = (b,h) 64x64 tile, 4 waves, wave w owns q rows [16w,16w+16).
// No Q/K/V LDS staging (each element read once; L2/L3-resident).
// QK: [tokens, 2048] bf16, Q at cols 0..1023 (h*64+d), K at cols 1024..2047.
// Vt: [1024, CROWS]  bf16, row f=h*64+d, col token.
// O overwrites the Q half in-place (safe: all Q/K reads complete before the
// P-repack __syncthreads; O region of block (b,h) read only by itself).
__global__ __launch_bounds__(256)
void attn_mfma(ushort* __restrict__ QK, const ushort* __restrict__ Vt,
               const float* __restrict__ bias, int CROWS) {
    const int t = threadIdx.x;
    const int lane = t & 63, wave = t >> 6;
    const int quad = lane >> 4, l16 = lane & 15;
    const int b = blockIdx.x >> 4, h = blockIdx.x & 15;
    const int SQK = 2048;
    const size_t qbase = (size_t)b * 64 * SQK + (size_t)h * 64;
    const size_t kbase = qbase + 1024;
    const size_t vbase = (size_t)(h * 64) * CROWS + (size_t)b * 64;

    __shared__ __attribute__((aligned(16))) ushort Pl[4 * 16 * 72];  // per-wave P[16][64], pad 72

    // ---- Q fragments: row=l16 (q within band), k(d)=ks*32+quad*8 ----
    bf16x8 qf[2];
#pragma unroll
    for (int ks = 0; ks < 2; ++ks)
        qf[ks] = *(const bf16x8*)&QK[qbase + (size_t)(wave * 16 + l16) * SQK + ks * 32 + quad * 8];

    // ---- S = Q K^T (contraction over d=64): M=16 q, N=64 kt ----
    const f32x4 zero = {0.f, 0.f, 0.f, 0.f};
    f32x4 s[4];
#pragma unroll
    for (int nt = 0; nt < 4; ++nt) s[nt] = zero;
#pragma unroll
    for (int nt = 0; nt < 4; ++nt)
#pragma unroll
        for (int ks = 0; ks < 2; ++ks) {
            bf16x8 kf = *(const bf16x8*)&QK[kbase + (size_t)(nt * 16 + l16) * SQK + ks * 32 + quad * 8];
            s[nt] = __builtin_amdgcn_mfma_f32_16x16x32_bf16(qf[ks], kf, s[nt], 0, 0, 0);
        }

    // ---- scale + bias; acc layout: row q = quad*4+r4 (+wave band), col kt = nt*16+l16 ----
    const int q0 = wave * 16 + quad * 4;
    float p[4][4];  // [nt][r4]
#pragma unroll
    for (int nt = 0; nt < 4; ++nt)
#pragma unroll
        for (int r4 = 0; r4 < 4; ++r4)
            p[nt][r4] = s[nt][r4] * 0.125f +
                        bias[(size_t)(h * 64 + q0 + r4) * 64 + nt * 16 + l16];

    // ---- row softmax: reduce over nt then across the 16 lanes of the quad ----
    float rinv[4];
#pragma unroll
    for (int r4 = 0; r4 < 4; ++r4) {
        float m = fmaxf(fmaxf(p[0][r4], p[1][r4]), fmaxf(p[2][r4], p[3][r4]));
        m = fmaxf(m, __shfl_xor(m, 1));
        m = fmaxf(m, __shfl_xor(m, 2));
        m = fmaxf(m, __shfl_xor(m, 4));
        m = fmaxf(m, __shfl_xor(m, 8));
#pragma unroll
        for (int nt = 0; nt < 4; ++nt) p[nt][r4] = __expf(p[nt][r4] - m);
        float sum = p[0][r4] + p[1][r4] + p[2][r4] + p[3][r4];
        sum += __shfl_xor(sum, 1);
        sum += __shfl_xor(sum, 2);
        sum += __shfl_xor(sum, 4);
        sum += __shfl_xor(sum, 8);
        rinv[r4] = 1.f / sum;
    }

    // ---- repack P to bf16 in LDS for the PV A-operand ----
#pragma unroll
    for (int nt = 0; nt < 4; ++nt)
#pragma unroll
        for (int r4 = 0; r4 < 4; ++r4)
            Pl[(wave * 16 + quad * 4 + r4) * 72 + nt * 16 + l16] = f2bf(p[nt][r4]);
    __syncthreads();

    // ---- O = P V (contraction over kt=64): M=16 q, N=64 d ----
    bf16x8 pa[2];
#pragma unroll
    for (int ks = 0; ks < 2; ++ks)
        pa[ks] = *(const bf16x8*)&Pl[(wave * 16 + l16) * 72 + ks * 32 + quad * 8];
    f32x4 o[4];
#pragma unroll
    for (int nt = 0; nt < 4; ++nt) o[nt] = zero;
#pragma unroll
    for (int nt = 0; nt < 4; ++nt)
#pragma unroll
        for (int ks = 0; ks < 2; ++ks) {
            bf16x8 vf = *(const bf16x8*)&Vt[vbase + (size_t)(nt * 16 + l16) * CROWS + ks * 32 + quad * 8];
            o[nt] = __builtin_amdgcn_mfma_f32_16x16x32_bf16(pa[ks], vf, o[nt], 0, 0, 0);
        }

    // ---- write O (deferred 1/l scaling) into Q half ----
#pragma unroll
    for (int nt = 0; nt < 4; ++nt)
#pragma unroll
        for (int r4 = 0; r4 < 4; ++r4)
            QK[qbase + (size_t)(q0 + r4) * SQK + nt * 16 + l16] = f2bf(o[nt][r4] * rinv[r4]);
}

extern "C" void kernel_launch(void* const* d_in, const int* in_sizes, int n_in,
                              void* d_out, int out_size, void* d_ws, size_t ws_size,
                              hipStream_t stream) {
    const float* x    = (const float*)d_in[0];   // [512,64,1024] f32
    const float* bias = (const float*)d_in[1];   // [1,16,64,64]  f32
    const float* Wq   = (const float*)d_in[2];
    const float* Wk   = (const float*)d_in[3];
    const float* Wv   = (const float*)d_in[4];
    const float* Wo   = (const float*)d_in[5];
    float* out = (float*)d_out;                  // [512,64,1024] f32

    const size_t D = 1024;
    const size_t WB = 4 * D * D * 2;             // 8.39 MB bf16 weights

    // ws-size-adaptive chunking: per chunk need CROWS*(2048+1024)*2 bytes after weights.
    int CHUNK_B = 128;                           // known-fit fallback (58.7 MB total)
    if (ws_size >= WB + (size_t)512 * 64 * 6144)      CHUNK_B = 512;
    else if (ws_size >= WB + (size_t)256 * 64 * 6144) CHUNK_B = 256;
    const int NCHUNK = 512 / CHUNK_B;
    const size_t CROWS = (size_t)CHUNK_B * 64;
    const size_t CELEM = CROWS * D;

    // ws layout: WqT|WkT (adjacent => fused [2048][1024]) | WvT | WoT | QKc | Vtc
    ushort* WqT = (ushort*)d_ws;
    ushort* WkT = WqT + D * D;
    ushort* WvT = WkT + D * D;
    ushort* WoT = WvT + D * D;
    ushort* QKc = WoT + D * D;                   // [CROWS][2048] bf16
    ushort* Vtc = QKc + CROWS * 2048;            // [1024][CROWS] bf16

    transpose1024<<<dim3(16, 16, 4), 256, 0, stream>>>(Wq, Wk, Wv, Wo, WqT, WkT, WvT, WoT);

    for (int c = 0; c < NCHUNK; ++c) {
        const float* xc = x + (size_t)c * CELEM;
        float* outc = out + (size_t)c * CELEM;
        ushort* Xc = (ushort*)outc;              // scratch: consumed before final GEMM writes
        cast_bf16<<<2048, 256, 0, stream>>>(xc, Xc, CELEM / 8);
        // fused Q|K projection: C[t][0..2047]
        gemm256<false><<<dim3(8, CROWS / 256), 512, 0, stream>>>(
            Xc, 1024, WqT, QKc, (int)CROWS, 2048, 1024);
        // transposed V projection: Vt[f][t] = sum_k WvT[f][k] * Xc[t][k]
        gemm256<false><<<dim3(CROWS / 256, 4), 512, 0, stream>>>(
            WvT, 1024, Xc, Vtc, 1024, (int)CROWS, 1024);
        // attention: O overwrites Q half of QKc
        attn_mfma<<<CHUNK_B * 16, 256, 0, stream>>>(QKc, Vtc, bias, (int)CROWS);
        // output projection: A = O (Q half, lda=2048)
        gemm256<true><<<dim3(4, CROWS / 256), 512, 0, stream>>>(
            QKc, 2048, WoT, outc, (int)CROWS, 1024, 1024);
    }
}

// Round 8
// 606.995 us; speedup vs baseline: 1.0695x; 1.0057x over previous
//
#include <hip/hip_runtime.h>
#include <hip/hip_bf16.h>
#include <stdint.h>

// ---------- bf16 helpers (raw ushort representation) ----------
__device__ inline float bf2f(ushort u) {
    union { uint32_t u; float f; } v; v.u = ((uint32_t)u) << 16; return v.f;
}
__device__ inline ushort f2bf(float f) {
    union { float f; uint32_t u; } v; v.f = f;
    uint32_t u = v.u;
    uint32_t r = (u + 0x7fffu + ((u >> 16) & 1u)) >> 16;  // RNE
    return (ushort)r;
}
__device__ inline uint32_t pk2bf(uint32_t flo, uint32_t fhi) {  // two f32 bit-patterns -> packed bf16x2
    uint32_t lo = (flo + 0x7fffu + ((flo >> 16) & 1u)) >> 16;
    uint32_t hi = (fhi + 0x7fffu + ((fhi >> 16) & 1u)) >> 16;
    return lo | (hi << 16);
}

typedef __attribute__((ext_vector_type(8))) short bf16x8;
typedef __attribute__((ext_vector_type(4))) float f32x4;

// async global->LDS, 16B per lane; LDS dest must be wave-uniform base (HW adds lane*16)
__device__ inline void gload_lds16(const ushort* g, ushort* l) {
    __builtin_amdgcn_global_load_lds(
        (const __attribute__((address_space(1))) void*)g,
        (__attribute__((address_space(3))) void*)l, 16, 0, 0);
}

// ---------- weight transpose+cast: W[1024,1024] f32 -> Wt[1024,1024] bf16 ----------
__global__ void transpose1024(const float* __restrict__ Wq, const float* __restrict__ Wk,
                              const float* __restrict__ Wv, const float* __restrict__ Wo,
                              ushort* __restrict__ WqT, ushort* __restrict__ WkT,
                              ushort* __restrict__ WvT, ushort* __restrict__ WoT) {
    const float* in; ushort* out;
    switch (blockIdx.z) {
        case 0: in = Wq; out = WqT; break;
        case 1: in = Wk; out = WkT; break;
        case 2: in = Wv; out = WvT; break;
        default: in = Wo; out = WoT; break;
    }
    __shared__ ushort tile[64][65];
    const int t = threadIdx.x;
    const int c = t & 63, rq = t >> 6;
    const int bx = blockIdx.x * 64, by = blockIdx.y * 64;
#pragma unroll
    for (int i = 0; i < 16; ++i) {
        int r = i * 4 + rq;
        tile[r][c] = f2bf(in[(size_t)(by + r) * 1024 + bx + c]);
    }
    __syncthreads();
#pragma unroll
    for (int i = 0; i < 16; ++i) {
        int r = i * 4 + rq;
        out[(size_t)(bx + r) * 1024 + by + c] = tile[c][r];
    }
}

// ---------- x chunk cast: f32 -> bf16, 8 elems/thread, grid-stride ----------
__global__ __launch_bounds__(256)
void cast_bf16(const float* __restrict__ in, ushort* __restrict__ out, size_t n8) {
    size_t i = (size_t)blockIdx.x * blockDim.x + threadIdx.x;
    const size_t stride = (size_t)gridDim.x * blockDim.x;
    for (; i < n8; i += stride) {
        const uint4 lo = *(const uint4*)&in[i * 8];
        const uint4 hi = *(const uint4*)&in[i * 8 + 4];
        uint4 o;
        o.x = pk2bf(lo.x, lo.y); o.y = pk2bf(lo.z, lo.w);
        o.z = pk2bf(hi.x, hi.y); o.w = pk2bf(hi.z, hi.w);
        *(uint4*)&out[i * 8] = o;
    }
}

// ---------- 256x256 8-phase bf16 GEMM: C[M,N] = A[M,K] @ Bt[N,K]^T ----------
// Round 8: M/N-SPLIT full-line staging (m201 geometry). Regions per buffer
// (ushort offsets): Ah0 @0 (A rows 0-127), Ah1 @8192, Bh0 @16384, Bh1 @24576;
// each [128 rows][64 cols] -> every staged row is a FULL 128B line (previous
// K-split gave 64B spans = 2x L2 transactions/byte; measured staging 11 B/cyc/CU
// vs m201's 47 -> this was the limiter hypothesis after T2/fences/chunking nulls).
// Wave (wm,wn) consumes exactly regions Ah(wm) and Bh(wn>>1).
// Swizzle (rule 21 both-sides): phys granule = logical ^ (row&7); inverse on the
// per-lane global source; ds_read 16 lanes -> 8 spans x 2 lanes = 2-way (free).
// Ledger (uniform issue order; barrier makes oldest-retirement global):
//   tile t phases P0..P3 stage next tile's Ah0,Ah1,Bh0,Bh1 into buf^1.
//   At tile start (P0): issue Ah0(t+2) first, then vmcnt(2) -> retires exactly
//   the 8 instrs of tile t's regions; barrier; then read frags. vmcnt(0) only
//   at the last tile. C-stores occur after the loop (don't perturb the ledger).
template <bool C_F32>
__global__ __launch_bounds__(512, 2)
void gemm256(const ushort* __restrict__ A, int lda, const ushort* __restrict__ Bt,
             void* __restrict__ C_, int M, int N, int K) {
    __shared__ __attribute__((aligned(16))) ushort lds[65536];  // 128 KiB
    const int t = threadIdx.x;
    const int lane = t & 63, wave = t >> 6;
    const int wm = wave >> 2, wn = wave & 3;       // 2 x 4 wave grid
    const int quad = lane >> 4, l16 = lane & 15;

    // bijective XCD swizzle (m204) on linear tile id
    const int gx = N >> 8;
    const int nwg = gridDim.x * gridDim.y;
    int wg = blockIdx.y * gridDim.x + blockIdx.x;
    {
        const int q = nwg >> 3, r = nwg & 7;
        const int xcd = wg & 7, loc = wg >> 3;
        wg = (xcd < r ? xcd * (q + 1) : r * (q + 1) + (xcd - r) * q) + loc;
    }
    const int m0 = (wg / gx) << 8, n0 = (wg % gx) << 8;

    const f32x4 zero = {0.f, 0.f, 0.f, 0.f};
    f32x4 acc[8][4];
#pragma unroll
    for (int i = 0; i < 8; ++i)
#pragma unroll
        for (int j = 0; j < 4; ++j) acc[i][j] = zero;

    // stage one 16KB region = [128 rows][64 cols], full-128B-line rows.
    // LDS slot (r, phys granule gp) holds logical granule gp ^ (r&7):
    // source col granule for linear slot g is (g&7) ^ (r&7).
    auto STAGE = [&](const ushort* __restrict__ src, int ldb, int rc0, int kcol,
                     int regio, int buf) {
        ushort* l = &lds[buf * 32768 + regio];
#pragma unroll
        for (int j = 0; j < 2; ++j) {
            const int g = j * 512 + t;
            const int r = g >> 3;
            const int cg = (((g & 7) ^ (r & 7)) * 8);
            gload_lds16(&src[(size_t)(rc0 + r) * ldb + kcol + cg],
                        &l[(j * 512 + wave * 64) * 8]);
        }
    };
    // swizzled ds_read offset: region-local row R (0-127), col granule gq (0-7)
    auto LOFF = [&](int R, int gq) { return R * 64 + ((gq ^ (R & 7)) * 8); };

    const int NT = K >> 6;
    // region-local row bases for this wave
    const int abase = wm * 8192;                   // Ah(wm)
    const int bbase = 16384 + (wn >> 1) * 8192;    // Bh(wn>>1)
    const int brow = (wn & 1) * 64;                // local row offset inside B-half

    // ---- prologue: stage tile 0 (4 regions), drain, barrier ----
    STAGE(A, lda, m0, 0, 0, 0);
    STAGE(A, lda, m0 + 128, 0, 8192, 0);
    STAGE(Bt, K, n0, 0, 16384, 0);
    STAGE(Bt, K, n0 + 128, 0, 24576, 0);
    asm volatile("s_waitcnt vmcnt(0)" ::: "memory");
    __builtin_amdgcn_s_barrier();

    int cur = 0;
    for (int kt = 0; kt < NT; ++kt) {
        const bool nx = kt + 1 < NT;
        const int kn = (kt + 1) << 6;
        const ushort* la = &lds[cur * 32768 + abase];
        const ushort* lb = &lds[cur * 32768 + bbase];
        bf16x8 af[4], bf[4];

        // ================= P0: checkpoint; ks0, mt 0-3 =================
        if (nx) STAGE(A, lda, m0, kn, 0, cur ^ 1);             // Ah0(next)
        if (kt > 0) {
            if (nx) asm volatile("s_waitcnt vmcnt(2)" ::: "memory");
            else    asm volatile("s_waitcnt vmcnt(0)" ::: "memory");
        }
        __builtin_amdgcn_s_barrier();
#pragma unroll
        for (int i = 0; i < 4; ++i) {
            af[i] = *(const bf16x8*)&la[LOFF(i * 16 + l16, quad)];
            bf[i] = *(const bf16x8*)&lb[LOFF(brow + i * 16 + l16, quad)];
        }
        __builtin_amdgcn_s_setprio(1);
#pragma unroll
        for (int i = 0; i < 4; ++i)
#pragma unroll
            for (int n = 0; n < 4; ++n)
                acc[i][n] = __builtin_amdgcn_mfma_f32_16x16x32_bf16(af[i], bf[n], acc[i][n], 0, 0, 0);
        __builtin_amdgcn_s_setprio(0);
        __builtin_amdgcn_s_barrier();

        // ================= P1: ks0, mt 4-7 =================
#pragma unroll
        for (int i = 0; i < 4; ++i)
            af[i] = *(const bf16x8*)&la[LOFF((i + 4) * 16 + l16, quad)];
        if (nx) STAGE(A, lda, m0 + 128, kn, 8192, cur ^ 1);    // Ah1(next)
        __builtin_amdgcn_s_barrier();
        __builtin_amdgcn_s_setprio(1);
#pragma unroll
        for (int i = 0; i < 4; ++i)
#pragma unroll
            for (int n = 0; n < 4; ++n)
                acc[i + 4][n] = __builtin_amdgcn_mfma_f32_16x16x32_bf16(af[i], bf[n], acc[i + 4][n], 0, 0, 0);
        __builtin_amdgcn_s_setprio(0);
        __builtin_amdgcn_s_barrier();

        // ================= P2: ks1, mt 0-3 =================
#pragma unroll
        for (int i = 0; i < 4; ++i) {
            af[i] = *(const bf16x8*)&la[LOFF(i * 16 + l16, 4 + quad)];
            bf[i] = *(const bf16x8*)&lb[LOFF(brow + i * 16 + l16, 4 + quad)];
        }
        if (nx) STAGE(Bt, K, n0, kn, 16384, cur ^ 1);          // Bh0(next)
        __builtin_amdgcn_s_barrier();
        __builtin_amdgcn_s_setprio(1);
#pragma unroll
        for (int i = 0; i < 4; ++i)
#pragma unroll
            for (int n = 0; n < 4; ++n)
                acc[i][n] = __builtin_amdgcn_mfma_f32_16x16x32_bf16(af[i], bf[n], acc[i][n], 0, 0, 0);
        __builtin_amdgcn_s_setprio(0);
        __builtin_amdgcn_s_barrier();

        // ================= P3: ks1, mt 4-7 =================
#pragma unroll
        for (int i = 0; i < 4; ++i)
            af[i] = *(const bf16x8*)&la[LOFF((i + 4) * 16 + l16, 4 + quad)];
        if (nx) STAGE(Bt, K, n0 + 128, kn, 24576, cur ^ 1);    // Bh1(next)
        __builtin_amdgcn_s_barrier();
        __builtin_amdgcn_s_setprio(1);
#pragma unroll
        for (int i = 0; i < 4; ++i)
#pragma unroll
            for (int n = 0; n < 4; ++n)
                acc[i + 4][n] = __builtin_amdgcn_mfma_f32_16x16x32_bf16(af[i], bf[n], acc[i + 4][n], 0, 0, 0);
        __builtin_amdgcn_s_setprio(0);
        __builtin_amdgcn_s_barrier();

        cur ^= 1;
    }

    // ---- epilogue: C/D layout col = lane&15, row = quad*4 + reg ----
#pragma unroll
    for (int mt = 0; mt < 8; ++mt)
#pragma unroll
        for (int nt = 0; nt < 4; ++nt)
#pragma unroll
            for (int r4 = 0; r4 < 4; ++r4) {
                const int row = m0 + wm * 128 + mt * 16 + quad * 4 + r4;
                const int col = n0 + wn * 64 + nt * 16 + l16;
                if (C_F32) ((float*)C_)[(size_t)row * N + col] = acc[mt][nt][r4];
                else       ((ushort*)C_)[(size_t)row * N + col] = f2bf(acc[mt][nt][r4]);
            }
}

// ---------- MFMA attention ----------
// Block = (b,h) 64x64 tile, 4 waves, wave w owns q rows [16w,16w+16).
// No Q/K/V LDS staging (each element read once; L2/L3-resident).
// QK: [tokens, 2048] bf16, Q at cols 0..1023 (h*64+d), K at cols 1024..2047.
// Vt: [1024, CROWS]  bf16, row f=h*64+d, col token.
// O overwrites the Q half in-place (safe: all Q/K reads complete before the
// P-repack __syncthreads; O region of block (b,h) read only by itself).
__global__ __launch_bounds__(256)
void attn_mfma(ushort* __restrict__ QK, const ushort* __restrict__ Vt,
               const float* __restrict__ bias, int CROWS) {
    const int t = threadIdx.x;
    const int lane = t & 63, wave = t >> 6;
    const int quad = lane >> 4, l16 = lane & 15;
    const int b = blockIdx.x >> 4, h = blockIdx.x & 15;
    const int SQK = 2048;
    const size_t qbase = (size_t)b * 64 * SQK + (size_t)h * 64;
    const size_t kbase = qbase + 1024;
    const size_t vbase = (size_t)(h * 64) * CROWS + (size_t)b * 64;

    __shared__ __attribute__((aligned(16))) ushort Pl[4 * 16 * 72];  // per-wave P[16][64], pad 72

    // ---- Q fragments: row=l16 (q within band), k(d)=ks*32+quad*8 ----
    bf16x8 qf[2];
#pragma unroll
    for (int ks = 0; ks < 2; ++ks)
        qf[ks] = *(const bf16x8*)&QK[qbase + (size_t)(wave * 16 + l16) * SQK + ks * 32 + quad * 8];

    // ---- S = Q K^T (contraction over d=64): M=16 q, N=64 kt ----
    const f32x4 zero = {0.f, 0.f, 0.f, 0.f};
    f32x4 s[4];
#pragma unroll
    for (int nt = 0; nt < 4; ++nt) s[nt] = zero;
#pragma unroll
    for (int nt = 0; nt < 4; ++nt)
#pragma unroll
        for (int ks = 0; ks < 2; ++ks) {
            bf16x8 kf = *(const bf16x8*)&QK[kbase + (size_t)(nt * 16 + l16) * SQK + ks * 32 + quad * 8];
            s[nt] = __builtin_amdgcn_mfma_f32_16x16x32_bf16(qf[ks], kf, s[nt], 0, 0, 0);
        }

    // ---- scale + bias; acc layout: row q = quad*4+r4 (+wave band), col kt = nt*16+l16 ----
    const int q0 = wave * 16 + quad * 4;
    float p[4][4];  // [nt][r4]
#pragma unroll
    for (int nt = 0; nt < 4; ++nt)
#pragma unroll
        for (int r4 = 0; r4 < 4; ++r4)
            p[nt][r4] = s[nt][r4] * 0.125f +
                        bias[(size_t)(h * 64 + q0 + r4) * 64 + nt * 16 + l16];

    // ---- row softmax: reduce over nt then across the 16 lanes of the quad ----
    float rinv[4];
#pragma unroll
    for (int r4 = 0; r4 < 4; ++r4) {
        float m = fmaxf(fmaxf(p[0][r4], p[1][r4]), fmaxf(p[2][r4], p[3][r4]));
        m = fmaxf(m, __shfl_xor(m, 1));
        m = fmaxf(m, __shfl_xor(m, 2));
        m = fmaxf(m, __shfl_xor(m, 4));
        m = fmaxf(m, __shfl_xor(m, 8));
#pragma unroll
        for (int nt = 0; nt < 4; ++nt) p[nt][r4] = __expf(p[nt][r4] - m);
        float sum = p[0][r4] + p[1][r4] + p[2][r4] + p[3][r4];
        sum += __shfl_xor(sum, 1);
        sum += __shfl_xor(sum, 2);
        sum += __shfl_xor(sum, 4);
        sum += __shfl_xor(sum, 8);
        rinv[r4] = 1.f / sum;
    }

    // ---- repack P to bf16 in LDS for the PV A-operand ----
#pragma unroll
    for (int nt = 0; nt < 4; ++nt)
#pragma unroll
        for (int r4 = 0; r4 < 4; ++r4)
            Pl[(wave * 16 + quad * 4 + r4) * 72 + nt * 16 + l16] = f2bf(p[nt][r4]);
    __syncthreads();

    // ---- O = P V (contraction over kt=64): M=16 q, N=64 d ----
    bf16x8 pa[2];
#pragma unroll
    for (int ks = 0; ks < 2; ++ks)
        pa[ks] = *(const bf16x8*)&Pl[(wave * 16 + l16) * 72 + ks * 32 + quad * 8];
    f32x4 o[4];
#pragma unroll
    for (int nt = 0; nt < 4; ++nt) o[nt] = zero;
#pragma unroll
    for (int nt = 0; nt < 4; ++nt)
#pragma unroll
        for (int ks = 0; ks < 2; ++ks) {
            bf16x8 vf = *(const bf16x8*)&Vt[vbase + (size_t)(nt * 16 + l16) * CROWS + ks * 32 + quad * 8];
            o[nt] = __builtin_amdgcn_mfma_f32_16x16x32_bf16(pa[ks], vf, o[nt], 0, 0, 0);
        }

    // ---- write O (deferred 1/l scaling) into Q half ----
#pragma unroll
    for (int nt = 0; nt < 4; ++nt)
#pragma unroll
        for (int r4 = 0; r4 < 4; ++r4)
            QK[qbase + (size_t)(q0 + r4) * SQK + nt * 16 + l16] = f2bf(o[nt][r4] * rinv[r4]);
}

extern "C" void kernel_launch(void* const* d_in, const int* in_sizes, int n_in,
                              void* d_out, int out_size, void* d_ws, size_t ws_size,
                              hipStream_t stream) {
    const float* x    = (const float*)d_in[0];   // [512,64,1024] f32
    const float* bias = (const float*)d_in[1];   // [1,16,64,64]  f32
    const float* Wq   = (const float*)d_in[2];
    const float* Wk   = (const float*)d_in[3];
    const float* Wv   = (const float*)d_in[4];
    const float* Wo   = (const float*)d_in[5];
    float* out = (float*)d_out;                  // [512,64,1024] f32

    const size_t D = 1024;
    const size_t WB = 4 * D * D * 2;             // 8.39 MB bf16 weights

    // ws-size-adaptive chunking: per chunk need CROWS*(2048+1024)*2 bytes after weights.
    int CHUNK_B = 128;                           // known-fit fallback (58.7 MB total)
    if (ws_size >= WB + (size_t)512 * 64 * 6144)      CHUNK_B = 512;
    else if (ws_size >= WB + (size_t)256 * 64 * 6144) CHUNK_B = 256;
    const int NCHUNK = 512 / CHUNK_B;
    const size_t CROWS = (size_t)CHUNK_B * 64;
    const size_t CELEM = CROWS * D;

    // ws layout: WqT|WkT (adjacent => fused [2048][1024]) | WvT | WoT | QKc | Vtc
    ushort* WqT = (ushort*)d_ws;
    ushort* WkT = WqT + D * D;
    ushort* WvT = WkT + D * D;
    ushort* WoT = WvT + D * D;
    ushort* QKc = WoT + D * D;                   // [CROWS][2048] bf16
    ushort* Vtc = QKc + CROWS * 2048;            // [1024][CROWS] bf16

    transpose1024<<<dim3(16, 16, 4), 256, 0, stream>>>(Wq, Wk, Wv, Wo, WqT, WkT, WvT, WoT);

    for (int c = 0; c < NCHUNK; ++c) {
        const float* xc = x + (size_t)c * CELEM;
        float* outc = out + (size_t)c * CELEM;
        ushort* Xc = (ushort*)outc;              // scratch: consumed before final GEMM writes
        cast_bf16<<<2048, 256, 0, stream>>>(xc, Xc, CELEM / 8);
        // fused Q|K projection: C[t][0..2047]
        gemm256<false><<<dim3(8, CROWS / 256), 512, 0, stream>>>(
            Xc, 1024, WqT, QKc, (int)CROWS, 2048, 1024);
        // transposed V projection: Vt[f][t] = sum_k WvT[f][k] * Xc[t][k]
        gemm256<false><<<dim3(CROWS / 256, 4), 512, 0, stream>>>(
            WvT, 1024, Xc, Vtc, 1024, (int)CROWS, 1024);
        // attention: O overwrites Q half of QKc
        attn_mfma<<<CHUNK_B * 16, 256, 0, stream>>>(QKc, Vtc, bias, (int)CROWS);
        // output projection: A = O (Q half, lda=2048)
        gemm256<true><<<dim3(4, CROWS / 256), 512, 0, stream>>>(
            QKc, 2048, WoT, outc, (int)CROWS, 1024, 1024);
    }
}

// Round 9
// 586.252 us; speedup vs baseline: 1.1073x; 1.0354x over previous
//
#include <hip/hip_runtime.h>
#include <hip/hip_bf16.h>
#include <stdint.h>

// ---------- bf16 helpers (raw ushort representation) ----------
__device__ inline float bf2f(ushort u) {
    union { uint32_t u; float f; } v; v.u = ((uint32_t)u) << 16; return v.f;
}
__device__ inline ushort f2bf(float f) {
    union { float f; uint32_t u; } v; v.f = f;
    uint32_t u = v.u;
    uint32_t r = (u + 0x7fffu + ((u >> 16) & 1u)) >> 16;  // RNE
    return (ushort)r;
}
__device__ inline uint32_t pk2bf(uint32_t flo, uint32_t fhi) {  // two f32 bit-patterns -> packed bf16x2
    uint32_t lo = (flo + 0x7fffu + ((flo >> 16) & 1u)) >> 16;
    uint32_t hi = (fhi + 0x7fffu + ((fhi >> 16) & 1u)) >> 16;
    return lo | (hi << 16);
}

typedef __attribute__((ext_vector_type(8))) short bf16x8;
typedef __attribute__((ext_vector_type(4))) float f32x4;

// async global->LDS, 16B per lane; LDS dest must be wave-uniform base (HW adds lane*16)
__device__ inline void gload_lds16(const ushort* g, ushort* l) {
    __builtin_amdgcn_global_load_lds(
        (const __attribute__((address_space(1))) void*)g,
        (__attribute__((address_space(3))) void*)l, 16, 0, 0);
}

// ---------- weight transpose+cast: W[1024,1024] f32 -> Wt[1024,1024] bf16 ----------
__global__ void transpose1024(const float* __restrict__ Wq, const float* __restrict__ Wk,
                              const float* __restrict__ Wv, const float* __restrict__ Wo,
                              ushort* __restrict__ WqT, ushort* __restrict__ WkT,
                              ushort* __restrict__ WvT, ushort* __restrict__ WoT) {
    const float* in; ushort* out;
    switch (blockIdx.z) {
        case 0: in = Wq; out = WqT; break;
        case 1: in = Wk; out = WkT; break;
        case 2: in = Wv; out = WvT; break;
        default: in = Wo; out = WoT; break;
    }
    __shared__ ushort tile[64][65];
    const int t = threadIdx.x;
    const int c = t & 63, rq = t >> 6;
    const int bx = blockIdx.x * 64, by = blockIdx.y * 64;
#pragma unroll
    for (int i = 0; i < 16; ++i) {
        int r = i * 4 + rq;
        tile[r][c] = f2bf(in[(size_t)(by + r) * 1024 + bx + c]);
    }
    __syncthreads();
#pragma unroll
    for (int i = 0; i < 16; ++i) {
        int r = i * 4 + rq;
        out[(size_t)(bx + r) * 1024 + by + c] = tile[c][r];
    }
}

// ---------- x chunk cast: f32 -> bf16, 8 elems/thread, grid-stride ----------
__global__ __launch_bounds__(256)
void cast_bf16(const float* __restrict__ in, ushort* __restrict__ out, size_t n8) {
    size_t i = (size_t)blockIdx.x * blockDim.x + threadIdx.x;
    const size_t stride = (size_t)gridDim.x * blockDim.x;
    for (; i < n8; i += stride) {
        const uint4 lo = *(const uint4*)&in[i * 8];
        const uint4 hi = *(const uint4*)&in[i * 8 + 4];
        uint4 o;
        o.x = pk2bf(lo.x, lo.y); o.y = pk2bf(lo.z, lo.w);
        o.z = pk2bf(hi.x, hi.y); o.w = pk2bf(hi.z, hi.w);
        *(uint4*)&out[i * 8] = o;
    }
}

// ---------- 256x256 8-phase bf16 GEMM: C[M,N] = A[M,K] @ Bt[N,K]^T ----------
// Round-8 structure UNCHANGED (control): M/N-split full-line staging, T2 granule
// swizzle (0 conflicts measured), counted vmcnt checkpoint at P0, setprio, XCD
// swizzle. Round 9 only changes the CALL SITES (fused N=3072 QKV projection).
template <bool C_F32>
__global__ __launch_bounds__(512, 2)
void gemm256(const ushort* __restrict__ A, int lda, const ushort* __restrict__ Bt,
             void* __restrict__ C_, int M, int N, int K) {
    __shared__ __attribute__((aligned(16))) ushort lds[65536];  // 128 KiB
    const int t = threadIdx.x;
    const int lane = t & 63, wave = t >> 6;
    const int wm = wave >> 2, wn = wave & 3;       // 2 x 4 wave grid
    const int quad = lane >> 4, l16 = lane & 15;

    // bijective XCD swizzle (m204) on linear tile id
    const int gx = N >> 8;
    const int nwg = gridDim.x * gridDim.y;
    int wg = blockIdx.y * gridDim.x + blockIdx.x;
    {
        const int q = nwg >> 3, r = nwg & 7;
        const int xcd = wg & 7, loc = wg >> 3;
        wg = (xcd < r ? xcd * (q + 1) : r * (q + 1) + (xcd - r) * q) + loc;
    }
    const int m0 = (wg / gx) << 8, n0 = (wg % gx) << 8;

    const f32x4 zero = {0.f, 0.f, 0.f, 0.f};
    f32x4 acc[8][4];
#pragma unroll
    for (int i = 0; i < 8; ++i)
#pragma unroll
        for (int j = 0; j < 4; ++j) acc[i][j] = zero;

    // stage one 16KB region = [128 rows][64 cols], full-128B-line rows.
    auto STAGE = [&](const ushort* __restrict__ src, int ldb, int rc0, int kcol,
                     int regio, int buf) {
        ushort* l = &lds[buf * 32768 + regio];
#pragma unroll
        for (int j = 0; j < 2; ++j) {
            const int g = j * 512 + t;
            const int r = g >> 3;
            const int cg = (((g & 7) ^ (r & 7)) * 8);
            gload_lds16(&src[(size_t)(rc0 + r) * ldb + kcol + cg],
                        &l[(j * 512 + wave * 64) * 8]);
        }
    };
    // swizzled ds_read offset: region-local row R (0-127), col granule gq (0-7)
    auto LOFF = [&](int R, int gq) { return R * 64 + ((gq ^ (R & 7)) * 8); };

    const int NT = K >> 6;
    const int abase = wm * 8192;                   // Ah(wm)
    const int bbase = 16384 + (wn >> 1) * 8192;    // Bh(wn>>1)
    const int brow = (wn & 1) * 64;                // local row offset inside B-half

    // ---- prologue: stage tile 0 (4 regions), drain, barrier ----
    STAGE(A, lda, m0, 0, 0, 0);
    STAGE(A, lda, m0 + 128, 0, 8192, 0);
    STAGE(Bt, K, n0, 0, 16384, 0);
    STAGE(Bt, K, n0 + 128, 0, 24576, 0);
    asm volatile("s_waitcnt vmcnt(0)" ::: "memory");
    __builtin_amdgcn_s_barrier();

    int cur = 0;
    for (int kt = 0; kt < NT; ++kt) {
        const bool nx = kt + 1 < NT;
        const int kn = (kt + 1) << 6;
        const ushort* la = &lds[cur * 32768 + abase];
        const ushort* lb = &lds[cur * 32768 + bbase];
        bf16x8 af[4], bf[4];

        // ================= P0: checkpoint; ks0, mt 0-3 =================
        if (nx) STAGE(A, lda, m0, kn, 0, cur ^ 1);             // Ah0(next)
        if (kt > 0) {
            if (nx) asm volatile("s_waitcnt vmcnt(2)" ::: "memory");
            else    asm volatile("s_waitcnt vmcnt(0)" ::: "memory");
        }
        __builtin_amdgcn_s_barrier();
#pragma unroll
        for (int i = 0; i < 4; ++i) {
            af[i] = *(const bf16x8*)&la[LOFF(i * 16 + l16, quad)];
            bf[i] = *(const bf16x8*)&lb[LOFF(brow + i * 16 + l16, quad)];
        }
        __builtin_amdgcn_s_setprio(1);
#pragma unroll
        for (int i = 0; i < 4; ++i)
#pragma unroll
            for (int n = 0; n < 4; ++n)
                acc[i][n] = __builtin_amdgcn_mfma_f32_16x16x32_bf16(af[i], bf[n], acc[i][n], 0, 0, 0);
        __builtin_amdgcn_s_setprio(0);
        __builtin_amdgcn_s_barrier();

        // ================= P1: ks0, mt 4-7 =================
#pragma unroll
        for (int i = 0; i < 4; ++i)
            af[i] = *(const bf16x8*)&la[LOFF((i + 4) * 16 + l16, quad)];
        if (nx) STAGE(A, lda, m0 + 128, kn, 8192, cur ^ 1);    // Ah1(next)
        __builtin_amdgcn_s_barrier();
        __builtin_amdgcn_s_setprio(1);
#pragma unroll
        for (int i = 0; i < 4; ++i)
#pragma unroll
            for (int n = 0; n < 4; ++n)
                acc[i + 4][n] = __builtin_amdgcn_mfma_f32_16x16x32_bf16(af[i], bf[n], acc[i + 4][n], 0, 0, 0);
        __builtin_amdgcn_s_setprio(0);
        __builtin_amdgcn_s_barrier();

        // ================= P2: ks1, mt 0-3 =================
#pragma unroll
        for (int i = 0; i < 4; ++i) {
            af[i] = *(const bf16x8*)&la[LOFF(i * 16 + l16, 4 + quad)];
            bf[i] = *(const bf16x8*)&lb[LOFF(brow + i * 16 + l16, 4 + quad)];
        }
        if (nx) STAGE(Bt, K, n0, kn, 16384, cur ^ 1);          // Bh0(next)
        __builtin_amdgcn_s_barrier();
        __builtin_amdgcn_s_setprio(1);
#pragma unroll
        for (int i = 0; i < 4; ++i)
#pragma unroll
            for (int n = 0; n < 4; ++n)
                acc[i][n] = __builtin_amdgcn_mfma_f32_16x16x32_bf16(af[i], bf[n], acc[i][n], 0, 0, 0);
        __builtin_amdgcn_s_setprio(0);
        __builtin_amdgcn_s_barrier();

        // ================= P3: ks1, mt 4-7 =================
#pragma unroll
        for (int i = 0; i < 4; ++i)
            af[i] = *(const bf16x8*)&la[LOFF((i + 4) * 16 + l16, 4 + quad)];
        if (nx) STAGE(Bt, K, n0 + 128, kn, 24576, cur ^ 1);    // Bh1(next)
        __builtin_amdgcn_s_barrier();
        __builtin_amdgcn_s_setprio(1);
#pragma unroll
        for (int i = 0; i < 4; ++i)
#pragma unroll
            for (int n = 0; n < 4; ++n)
                acc[i + 4][n] = __builtin_amdgcn_mfma_f32_16x16x32_bf16(af[i], bf[n], acc[i + 4][n], 0, 0, 0);
        __builtin_amdgcn_s_setprio(0);
        __builtin_amdgcn_s_barrier();

        cur ^= 1;
    }

    // ---- epilogue: C/D layout col = lane&15, row = quad*4 + reg ----
#pragma unroll
    for (int mt = 0; mt < 8; ++mt)
#pragma unroll
        for (int nt = 0; nt < 4; ++nt)
#pragma unroll
            for (int r4 = 0; r4 < 4; ++r4) {
                const int row = m0 + wm * 128 + mt * 16 + quad * 4 + r4;
                const int col = n0 + wn * 64 + nt * 16 + l16;
                if (C_F32) ((float*)C_)[(size_t)row * N + col] = acc[mt][nt][r4];
                else       ((ushort*)C_)[(size_t)row * N + col] = f2bf(acc[mt][nt][r4]);
            }
}

// ---------- MFMA attention (fused-QKV layout) ----------
// Block = (b,h) 64x64 tile, 4 waves, wave w owns q rows [16w,16w+16).
// QKV: [tokens, 3072] bf16; Q cols 0..1023 (h*64+d), K cols 1024..2047,
// V cols 2048..3071. V tile is staged through LDS with a TRANSPOSED write
// (Vt_lds[d][tok], pad 72, XOR-granule swizzle: phys_gran = (tok>>3)^((d>>3)&7);
// derived conflict-free writes, 2-way b128 reads, 16B-aligned). V global loads
// are issued at kernel top so QK^T + softmax hide their latency; the single
// existing __syncthreads covers both P-repack and V-transpose publication.
// O overwrites the Q half in-place (all Q/K reads complete before the barrier;
// block (b,h)'s O region is read only by itself).
__global__ __launch_bounds__(256)
void attn_mfma(ushort* __restrict__ QKV, const float* __restrict__ bias, int CROWS) {
    const int t = threadIdx.x;
    const int lane = t & 63, wave = t >> 6;
    const int quad = lane >> 4, l16 = lane & 15;
    const int b = blockIdx.x >> 4, h = blockIdx.x & 15;
    const int SQK = 3072;
    const size_t qbase = (size_t)b * 64 * SQK + (size_t)h * 64;
    const size_t kbase = qbase + 1024;

    __shared__ __attribute__((aligned(16))) ushort Pl[4 * 16 * 72];  // per-wave P[16][64]
    __shared__ __attribute__((aligned(16))) ushort Vt[64 * 72];      // V^T[d][tok], swizzled

    // ---- issue V tile loads early (latency hidden under QK^T/softmax) ----
    bf16x8 vstage[2];
#pragma unroll
    for (int i = 0; i < 2; ++i) {
        const int s = i * 256 + t;
        const int tok = s >> 3, g = s & 7;
        vstage[i] = *(const bf16x8*)&QKV[(size_t)(b * 64 + tok) * SQK + 2048 + h * 64 + g * 8];
    }

    // ---- Q fragments: row=l16 (q within band), k(d)=ks*32+quad*8 ----
    bf16x8 qf[2];
#pragma unroll
    for (int ks = 0; ks < 2; ++ks)
        qf[ks] = *(const bf16x8*)&QKV[qbase + (size_t)(wave * 16 + l16) * SQK + ks * 32 + quad * 8];

    // ---- S = Q K^T (contraction over d=64): M=16 q, N=64 kt ----
    const f32x4 zero = {0.f, 0.f, 0.f, 0.f};
    f32x4 s[4];
#pragma unroll
    for (int nt = 0; nt < 4; ++nt) s[nt] = zero;
#pragma unroll
    for (int nt = 0; nt < 4; ++nt)
#pragma unroll
        for (int ks = 0; ks < 2; ++ks) {
            bf16x8 kf = *(const bf16x8*)&QKV[kbase + (size_t)(nt * 16 + l16) * SQK + ks * 32 + quad * 8];
            s[nt] = __builtin_amdgcn_mfma_f32_16x16x32_bf16(qf[ks], kf, s[nt], 0, 0, 0);
        }

    // ---- scale + bias; acc layout: row q = quad*4+r4 (+wave band), col kt = nt*16+l16 ----
    const int q0 = wave * 16 + quad * 4;
    float p[4][4];  // [nt][r4]
#pragma unroll
    for (int nt = 0; nt < 4; ++nt)
#pragma unroll
        for (int r4 = 0; r4 < 4; ++r4)
            p[nt][r4] = s[nt][r4] * 0.125f +
                        bias[(size_t)(h * 64 + q0 + r4) * 64 + nt * 16 + l16];

    // ---- row softmax: reduce over nt then across the 16 lanes of the quad ----
    float rinv[4];
#pragma unroll
    for (int r4 = 0; r4 < 4; ++r4) {
        float m = fmaxf(fmaxf(p[0][r4], p[1][r4]), fmaxf(p[2][r4], p[3][r4]));
        m = fmaxf(m, __shfl_xor(m, 1));
        m = fmaxf(m, __shfl_xor(m, 2));
        m = fmaxf(m, __shfl_xor(m, 4));
        m = fmaxf(m, __shfl_xor(m, 8));
#pragma unroll
        for (int nt = 0; nt < 4; ++nt) p[nt][r4] = __expf(p[nt][r4] - m);
        float sum = p[0][r4] + p[1][r4] + p[2][r4] + p[3][r4];
        sum += __shfl_xor(sum, 1);
        sum += __shfl_xor(sum, 2);
        sum += __shfl_xor(sum, 4);
        sum += __shfl_xor(sum, 8);
        rinv[r4] = 1.f / sum;
    }

    // ---- repack P to bf16 in LDS for the PV A-operand ----
#pragma unroll
    for (int nt = 0; nt < 4; ++nt)
#pragma unroll
        for (int r4 = 0; r4 < 4; ++r4)
            Pl[(wave * 16 + quad * 4 + r4) * 72 + nt * 16 + l16] = f2bf(p[nt][r4]);

    // ---- transposed V write: (tok, d=g*8+j) -> Vt[d][tok] swizzled ----
#pragma unroll
    for (int i = 0; i < 2; ++i) {
        const int s = i * 256 + t;
        const int tok = s >> 3, g = s & 7;
#pragma unroll
        for (int j = 0; j < 8; ++j) {
            const int d = g * 8 + j;
            Vt[d * 72 + (((tok >> 3) ^ ((d >> 3) & 7)) << 3) + (tok & 7)] =
                (ushort)vstage[i][j];
        }
    }
    __syncthreads();

    // ---- O = P V (contraction over kt=64): M=16 q, N=64 d ----
    bf16x8 pa[2];
#pragma unroll
    for (int ks = 0; ks < 2; ++ks)
        pa[ks] = *(const bf16x8*)&Pl[(wave * 16 + l16) * 72 + ks * 32 + quad * 8];
    f32x4 o[4];
#pragma unroll
    for (int nt = 0; nt < 4; ++nt) o[nt] = zero;
#pragma unroll
    for (int nt = 0; nt < 4; ++nt)
#pragma unroll
        for (int ks = 0; ks < 2; ++ks) {
            const int d = nt * 16 + l16;
            bf16x8 vf = *(const bf16x8*)&Vt[d * 72 + (((ks * 4 + quad) ^ ((d >> 3) & 7)) << 3)];
            o[nt] = __builtin_amdgcn_mfma_f32_16x16x32_bf16(pa[ks], vf, o[nt], 0, 0, 0);
        }

    // ---- write O (deferred 1/l scaling) into Q half ----
#pragma unroll
    for (int nt = 0; nt < 4; ++nt)
#pragma unroll
        for (int r4 = 0; r4 < 4; ++r4)
            QKV[qbase + (size_t)(q0 + r4) * SQK + nt * 16 + l16] = f2bf(o[nt][r4] * rinv[r4]);
}

extern "C" void kernel_launch(void* const* d_in, const int* in_sizes, int n_in,
                              void* d_out, int out_size, void* d_ws, size_t ws_size,
                              hipStream_t stream) {
    const float* x    = (const float*)d_in[0];   // [512,64,1024] f32
    const float* bias = (const float*)d_in[1];   // [1,16,64,64]  f32
    const float* Wq   = (const float*)d_in[2];
    const float* Wk   = (const float*)d_in[3];
    const float* Wv   = (const float*)d_in[4];
    const float* Wo   = (const float*)d_in[5];
    float* out = (float*)d_out;                  // [512,64,1024] f32

    const size_t D = 1024;
    const size_t WB = 4 * D * D * 2;             // 8.39 MB bf16 weights

    // ws-size-adaptive chunking: per chunk need CROWS*3072*2 bytes after weights
    // (identical budget to the old QKc+Vtc layout).
    int CHUNK_B = 128;                           // known-fit fallback
    if (ws_size >= WB + (size_t)512 * 64 * 6144)      CHUNK_B = 512;
    else if (ws_size >= WB + (size_t)256 * 64 * 6144) CHUNK_B = 256;
    const int NCHUNK = 512 / CHUNK_B;
    const size_t CROWS = (size_t)CHUNK_B * 64;
    const size_t CELEM = CROWS * D;

    // ws layout: WqT|WkT|WvT (contiguous => fused [3072][1024] B-matrix) | WoT | QKVc
    ushort* WqT  = (ushort*)d_ws;
    ushort* WkT  = WqT + D * D;
    ushort* WvT  = WkT + D * D;
    ushort* WoT  = WvT + D * D;
    ushort* QKVc = WoT + D * D;                  // [CROWS][3072] bf16 (201 MB @ 512)

    transpose1024<<<dim3(16, 16, 4), 256, 0, stream>>>(Wq, Wk, Wv, Wo, WqT, WkT, WvT, WoT);

    for (int c = 0; c < NCHUNK; ++c) {
        const float* xc = x + (size_t)c * CELEM;
        float* outc = out + (size_t)c * CELEM;
        ushort* Xc = (ushort*)outc;              // scratch: consumed before final GEMM writes
        cast_bf16<<<2048, 256, 0, stream>>>(xc, Xc, CELEM / 8);
        // fused Q|K|V projection: C[t][0..3071]
        gemm256<false><<<dim3(12, CROWS / 256), 512, 0, stream>>>(
            Xc, 1024, WqT, QKVc, (int)CROWS, 3072, 1024);
        // attention: O overwrites Q third of QKVc
        attn_mfma<<<CHUNK_B * 16, 256, 0, stream>>>(QKVc, bias, (int)CROWS);
        // output projection: A = O (Q third, lda=3072)
        gemm256<true><<<dim3(4, CROWS / 256), 512, 0, stream>>>(
            QKVc, 3072, WoT, outc, (int)CROWS, 1024, 1024);
    }
}